// Round 2
// baseline (48193.900 us; speedup 1.0000x reference)
//
#include <hip/hip_runtime.h>
#include <math.h>

#define BB 128
#define SS 512
#define TT 128
#define FF 64
#define HH 1024

#define NBLK 256   // 2 b-tiles x 128 j-blocks  (exactly 1 block/CU -> co-resident)
#define NTHR 256   // 32 bgroups(2 b each) x 8 jlanes
#define BK 64
#define LDP 68     // padded leading dim (floats): +4 keeps 16B align, kills conflicts

// ---------------- grid barrier (device-scope, monotonic counter) ----------------
// All NBLK blocks are co-resident by construction (1 block/CU), so a plain
// launch + hand-rolled barrier is safe; no cooperative launch needed.
__device__ __forceinline__ void gridbar(unsigned* bar, unsigned* barno){
  __syncthreads();
  if (threadIdx.x == 0){
    __threadfence();                       // release: L2 writeback, device-scope visibility
    atomicAdd(bar, 1u);
    unsigned tgt = ++(*barno) * (unsigned)NBLK;
    while (__hip_atomic_load(bar, __ATOMIC_RELAXED, __HIP_MEMORY_SCOPE_AGENT) < tgt){
      __builtin_amdgcn_s_sleep(1);
    }
    __threadfence();                       // acquire: invalidate stale cached lines
  }
  __syncthreads();
}

// ---------------- tiled GEMM accumulation over k-chunks ----------------
// A: 64 rows (this block's b-tile) x nchunk*64 cols, row stride lda
// W: gate-major weights; block uses rows gr = g*HH + jbase + jl (g<4, jl<8), stride ldw
// acc[bi*4+g] += sum_k A[b_local(bi)][k] * W[gr][k]
__device__ __forceinline__ void mm_chunks(
    const float* __restrict__ A, int lda,
    const float* __restrict__ W, int ldw,
    int nchunk, int jbase,
    float (*ht)[LDP], float (*wt)[LDP],
    float acc[8])
{
  const int tid   = threadIdx.x;
  const int jlane = tid & 7;
  const int bg    = tid >> 3;
  float4 pa[4], pw[2];

  // prefetch chunk 0 into registers
  #pragma unroll
  for (int i=0;i<4;i++){ int slot = tid + i*NTHR; int r = slot>>4; int c4 = slot&15;
    pa[i] = *(const float4*)(A + (size_t)r*lda + c4*4); }
  #pragma unroll
  for (int i=0;i<2;i++){ int slot = tid + i*NTHR; int r = slot>>4; int c4 = slot&15;
    int gr = (r>>3)*HH + jbase + (r&7);
    pw[i] = *(const float4*)(W + (size_t)gr*ldw + c4*4); }

  for (int c=0; c<nchunk; c++){
    __syncthreads();  // LDS free to overwrite
    #pragma unroll
    for (int i=0;i<4;i++){ int slot = tid + i*NTHR; int r = slot>>4; int c4 = slot&15;
      *(float4*)&ht[r][c4*4] = pa[i]; }
    #pragma unroll
    for (int i=0;i<2;i++){ int slot = tid + i*NTHR; int r = slot>>4; int c4 = slot&15;
      *(float4*)&wt[r][c4*4] = pw[i]; }
    __syncthreads();

    if (c+1 < nchunk){            // prefetch next chunk while computing this one
      int cb = (c+1)*BK;
      #pragma unroll
      for (int i=0;i<4;i++){ int slot = tid + i*NTHR; int r = slot>>4; int c4 = slot&15;
        pa[i] = *(const float4*)(A + (size_t)r*lda + cb + c4*4); }
      #pragma unroll
      for (int i=0;i<2;i++){ int slot = tid + i*NTHR; int r = slot>>4; int c4 = slot&15;
        int gr = (r>>3)*HH + jbase + (r&7);
        pw[i] = *(const float4*)(W + (size_t)gr*ldw + cb + c4*4); }
    }

    const float* h0p = &ht[bg*2  ][0];
    const float* h1p = &ht[bg*2+1][0];
    #pragma unroll
    for (int kk=0; kk<BK; kk+=4){
      float4 hv0 = *(const float4*)(h0p + kk);
      float4 hv1 = *(const float4*)(h1p + kk);
      #pragma unroll
      for (int g=0; g<4; g++){
        float4 wv = *(const float4*)&wt[g*8 + jlane][kk];
        acc[0*4+g] = fmaf(hv0.x, wv.x, fmaf(hv0.y, wv.y, fmaf(hv0.z, wv.z, fmaf(hv0.w, wv.w, acc[0*4+g]))));
        acc[1*4+g] = fmaf(hv1.x, wv.x, fmaf(hv1.y, wv.y, fmaf(hv1.z, wv.z, fmaf(hv1.w, wv.w, acc[1*4+g]))));
      }
    }
  }
}

__device__ __forceinline__ float sigm(float x){ return 1.f/(1.f+expf(-x)); }

// ---------------- persistent fused seq2seq kernel ----------------
__global__ __launch_bounds__(NTHR)
void seq2seq_kernel(const float* __restrict__ src, const float* __restrict__ tgt,
  const float* __restrict__ eWih, const float* __restrict__ eWhh,
  const float* __restrict__ ebih, const float* __restrict__ ebhh,
  const float* __restrict__ dWih, const float* __restrict__ dWhh,
  const float* __restrict__ dbih, const float* __restrict__ dbhh,
  const float* __restrict__ fcW, const float* __restrict__ fcb,
  float* __restrict__ out, float* hbuf, float* pred, unsigned* bar)
{
  __shared__ __align__(16) float ht[64][LDP];
  __shared__ __align__(16) float wt[32][LDP];

  const int tid   = threadIdx.x;
  const int blk   = blockIdx.x;
  const int btile = blk >> 7;        // 0..1
  const int jblk  = blk & 127;       // 0..127
  const int jbase = jblk * 8;
  const int jlane = tid & 7;
  const int bg    = tid >> 3;        // 0..31
  const int b0    = btile*64 + bg*2;
  const int b1    = b0 + 1;
  const int j     = jbase + jlane;
  unsigned barno  = 0;

  // ---- init (ws + out are poisoned 0xAA every call) ----
  for (int idx = blk*NTHR + tid; idx < BB*HH; idx += NBLK*NTHR) hbuf[idx] = 0.f; // h0 = 0
  if (blk == 0){
    for (int b = tid; b < BB; b += NTHR){
      out[(size_t)b*TT] = 0.f;           // outputs[:,0] = 0
      pred[0*BB + b] = tgt[(size_t)b*TT];// x0 = target[:,0,0]
      pred[1*BB + b] = fcb[0];           // accumulation target of dec step 0
      pred[2*BB + b] = 0.f;
    }
  }
  gridbar(bar, &barno);

  // ---- encoder: 512 steps; c lives in registers the whole time ----
  float c0r = 0.f, c1r = 0.f;
  float ebias[4];
  #pragma unroll
  for (int g=0; g<4; g++) ebias[g] = ebih[g*HH + j] + ebhh[g*HH + j];

  int p = 0;
  for (int t=0; t<SS; t++){
    float acc[8];
    #pragma unroll
    for (int i=0;i<8;i++) acc[i]=0.f;
    mm_chunks(hbuf + (size_t)p*BB*HH + (size_t)(btile*64)*HH, HH, eWhh, HH, 16, jbase, ht, wt, acc);
    mm_chunks(src + (size_t)(btile*64)*SS*FF + (size_t)t*FF, SS*FF, eWih, FF, 1, jbase, ht, wt, acc);

    float* hdst = hbuf + (size_t)(p^1)*BB*HH;
    float h2v[2];
    #pragma unroll
    for (int bi=0; bi<2; bi++){
      float gi = acc[bi*4+0] + ebias[0];
      float gf = acc[bi*4+1] + ebias[1];
      float gg = acc[bi*4+2] + ebias[2];
      float go = acc[bi*4+3] + ebias[3];
      float si = sigm(gi), sf = sigm(gf), so = sigm(go);
      float tg = tanhf(gg);
      float cr = (bi ? c1r : c0r);
      cr = sf*cr + si*tg;
      if (bi) c1r = cr; else c0r = cr;
      h2v[bi] = so * tanhf(cr);
    }
    hdst[(size_t)b0*HH + j] = h2v[0];
    hdst[(size_t)b1*HH + j] = h2v[1];
    p ^= 1;
    gridbar(bar, &barno);
  }

  // ---- decoder: 127 steps, scalar autoregressive input via rotating pred[3] ----
  float dbias[4], dwih[4];
  #pragma unroll
  for (int g=0; g<4; g++){
    dbias[g] = dbih[g*HH + j] + dbhh[g*HH + j];
    dwih[g]  = dWih[g*HH + j];          // dec_Wih is (4H, 1)
  }
  const float fcwv = fcW[j];
  const float fcbv = fcb[0];

  for (int t=0; t<TT-1; t++){
    const float* pcur = pred + (t%3)*BB;       // x for this step (complete)
    float*       pnxt = pred + ((t+1)%3)*BB;   // atomically accumulated this step
    float*       pzro = pred + ((t+2)%3)*BB;   // untouched this step -> re-init
    float x0 = pcur[b0], x1 = pcur[b1];
    if (jblk==0 && jlane==0 && t>0){           // out[:,t] = pred from step t-1
      out[(size_t)b0*TT + t] = x0;
      out[(size_t)b1*TT + t] = x1;
    }
    float acc[8];
    #pragma unroll
    for (int i=0;i<8;i++) acc[i]=0.f;
    mm_chunks(hbuf + (size_t)p*BB*HH + (size_t)(btile*64)*HH, HH, dWhh, HH, 16, jbase, ht, wt, acc);

    float* hdst = hbuf + (size_t)(p^1)*BB*HH;
    float pp[2];
    #pragma unroll
    for (int bi=0; bi<2; bi++){
      float xb = bi ? x1 : x0;
      float gi = acc[bi*4+0] + dbias[0] + xb*dwih[0];
      float gf = acc[bi*4+1] + dbias[1] + xb*dwih[1];
      float gg = acc[bi*4+2] + dbias[2] + xb*dwih[2];
      float go = acc[bi*4+3] + dbias[3] + xb*dwih[3];
      float si = sigm(gi), sf = sigm(gf), so = sigm(go);
      float tg = tanhf(gg);
      float cr = (bi ? c1r : c0r);
      cr = sf*cr + si*tg;
      if (bi) c1r = cr; else c0r = cr;
      float h2 = so * tanhf(cr);
      if (bi) hdst[(size_t)b1*HH + j] = h2; else hdst[(size_t)b0*HH + j] = h2;
      pp[bi] = h2 * fcwv;
    }
    // reduce fc partial over the 8 jlanes (consecutive lanes), then 1 atomic per b
    #pragma unroll
    for (int d=4; d>0; d>>=1){
      pp[0] += __shfl_down(pp[0], d, 8);
      pp[1] += __shfl_down(pp[1], d, 8);
    }
    if (jlane == 0){
      atomicAdd(&pnxt[b0], pp[0]);
      atomicAdd(&pnxt[b1], pp[1]);
    }
    if (jblk==0 && jlane==0){ pzro[b0] = fcbv; pzro[b1] = fcbv; } // pre-init for step t+1's target
    p ^= 1;
    gridbar(bar, &barno);
  }
  // final column T-1
  if (jblk==0 && jlane==0){
    const float* pl = pred + ((TT-1)%3)*BB;
    out[(size_t)b0*TT + (TT-1)] = pl[b0];
    out[(size_t)b1*TT + (TT-1)] = pl[b1];
  }
}

extern "C" void kernel_launch(void* const* d_in, const int* in_sizes, int n_in,
                              void* d_out, int out_size, void* d_ws, size_t ws_size,
                              hipStream_t stream){
  (void)in_sizes; (void)n_in; (void)out_size; (void)ws_size;
  const float* src  = (const float*)d_in[0];
  const float* tgt  = (const float*)d_in[1];
  const float* eWih = (const float*)d_in[2];
  const float* eWhh = (const float*)d_in[3];
  const float* ebih = (const float*)d_in[4];
  const float* ebhh = (const float*)d_in[5];
  const float* dWih = (const float*)d_in[6];
  const float* dWhh = (const float*)d_in[7];
  const float* dbih = (const float*)d_in[8];
  const float* dbhh = (const float*)d_in[9];
  const float* fcW  = (const float*)d_in[10];
  const float* fcb  = (const float*)d_in[11];
  float* out  = (float*)d_out;
  float* ws   = (float*)d_ws;
  float* hbuf = ws;                        // 2 * 128 * 1024 floats (h ping-pong)
  float* pred = ws + 2*BB*HH;              // 3 * 128 floats (rotating x/pred)
  unsigned* bar = (unsigned*)(ws + 2*BB*HH + 3*BB);
  hipMemsetAsync(bar, 0, sizeof(unsigned), stream);  // ws is poisoned every call
  seq2seq_kernel<<<dim3(NBLK), dim3(NTHR), 0, stream>>>(
      src, tgt, eWih, eWhh, ebih, ebhh, dWih, dWhh, dbih, dbhh,
      fcW, fcb, out, hbuf, pred, bar);
}

// Round 3
// 22050.253 us; speedup vs baseline: 2.1856x; 2.1856x over previous
//
#include <hip/hip_runtime.h>
#include <hip/hip_fp16.h>
#include <math.h>

#define BB 128
#define SS 512
#define TT 128
#define FF 64
#define HH 1024

#define NBLK 128   // 1 block/CU on 128 of 256 CUs -> co-resident, hand-rolled grid barrier OK
#define NTHR 256   // 4 waves

typedef _Float16 half8 __attribute__((ext_vector_type(8)));
typedef float    f32x4 __attribute__((ext_vector_type(4)));

// ---------------- grid barrier (device-scope, monotonic counter) ----------------
__device__ __forceinline__ void gridbar(unsigned* bar, unsigned* barno){
  __syncthreads();
  if (threadIdx.x == 0){
    __threadfence();                       // release: make h stores visible device-wide
    atomicAdd(bar, 1u);
    unsigned tgt = ++(*barno) * (unsigned)NBLK;
    while (__hip_atomic_load(bar, __ATOMIC_RELAXED, __HIP_MEMORY_SCOPE_AGENT) < tgt){
      __builtin_amdgcn_s_sleep(1);
    }
    __threadfence();                       // acquire: invalidate stale cached lines
  }
  __syncthreads();
}

__device__ __forceinline__ float sigm(float x){ return 1.f/(1.f+expf(-x)); }

// ---------------- fp32 -> fp16 conversion pre-kernel ----------------
__global__ __launch_bounds__(NTHR) void cvt_f32_f16(const float* __restrict__ s,
                                                    ushort* __restrict__ d, int n){
  for (int i = blockIdx.x*NTHR + threadIdx.x; i < n; i += gridDim.x*NTHR)
    d[i] = __half_as_ushort(__float2half(s[i]));
}

// ---------------- persistent fused seq2seq kernel (fp16 MFMA) ----------------
__global__ __launch_bounds__(NTHR) void seq_kernel(
  const float*  __restrict__ tgt,
  const ushort* __restrict__ src16,    // [B][S*F] fp16
  const ushort* __restrict__ wih16,    // [4H][F]  fp16
  const ushort* __restrict__ ewhh16,   // [4H][H]  fp16
  const ushort* __restrict__ dwhh16,   // [4H][H]  fp16
  const float* __restrict__ ebih, const float* __restrict__ ebhh,
  const float* __restrict__ dWih,
  const float* __restrict__ dbih, const float* __restrict__ dbhh,
  const float* __restrict__ fcW, const float* __restrict__ fcb,
  float* __restrict__ out, ushort* h16, float* pred, unsigned* bar)
{
  // LDS: padded rows of 72 halves (144 B) -> all frag reads <=2-way bank aliasing (free)
  __shared__ __align__(16) ushort At[2][128*72];   // A (h or x) chunk, dbuf: 2x18 KB
  __shared__ __align__(16) ushort Bt[2][32*72];    // Whh chunk, dbuf: 2x4.5 KB
  __shared__ __align__(16) ushort Wt[32*72];       // Wih tile (persistent)
  __shared__ float predacc[BB];
  float* Ct = (float*)&At[0][0];                   // epilogue scratch aliases At (dead then)

  const int tid = threadIdx.x;
  const int w   = tid >> 6;          // wave 0..3 : owns C rows w*32..w*32+31, stages gate g=w of B
  const int l   = tid & 63;
  const int jbase = blockIdx.x * 8;  // this block's 8 hidden columns
  const int sr = l >> 3, sk = l & 7; // staging: row-in-8, kgroup
  const int fr = l & 15, fq = l >> 4;// frag: row, k-quad
  const int bb = tid & 31, jl = tid >> 5;
  const int jg = jbase + jl;
  unsigned barno = 0;

  // ---- init (ws/out poisoned every call) ----
  { uint* hz = (uint*)h16;           // zero h ping buffer 0
    for (int i = blockIdx.x*NTHR + tid; i < BB*HH/2; i += NBLK*NTHR) hz[i] = 0u; }
  if (blockIdx.x == 0 && tid < BB){
    out[(size_t)tid*TT] = 0.f;           // outputs[:,0] = 0
    pred[0*BB + tid] = tgt[(size_t)tid*TT];  // x0 = target[:,0,0]
    pred[1*BB + tid] = fcb[0];               // acc target of dec step 0
    pred[2*BB + tid] = 0.f;
  }
  // preload Wih tile (rows ordered g*8+jl), once
  { uint4 v = *(const uint4*)(wih16 + (size_t)(w*HH + jbase + sr)*FF + sk*8);
    *(uint4*)(&Wt[(w*8+sr)*72 + sk*8]) = v; }

  float ebias[4], dbias[4], dwihv[4];
  #pragma unroll
  for (int g=0; g<4; g++){
    ebias[g] = ebih[g*HH + jg] + ebhh[g*HH + jg];
    dbias[g] = dbih[g*HH + jg] + dbhh[g*HH + jg];
    dwihv[g] = dWih[g*HH + jg];
  }
  const float fcwv = fcW[jg];
  const float fcbv = fcb[0];

  float cc[4] = {0.f,0.f,0.f,0.f};   // cell state lives in registers for all 639 steps
  int p = 0;
  gridbar(bar, &barno);

  for (int t = 0; t < SS+TT-1; t++){
    const bool enc = (t < SS);
    const ushort* hsrc = h16 + (size_t)p*BB*HH;
    const ushort* bw   = enc ? ewhh16 : dwhh16;
    const int NC = enc ? 17 : 16;    // 16 h-chunks (+1 x-chunk for encoder)

    // register prefetch of chunk 0
    uint4 ra[4]; uint4 rb;
    #pragma unroll
    for (int q=0;q<4;q++)
      ra[q] = *(const uint4*)(hsrc + (size_t)(w*32+q*8+sr)*HH + sk*8);
    rb = *(const uint4*)(bw + (size_t)(w*HH + jbase + sr)*HH + sk*8);

    f32x4 acc[2][2];
    #pragma unroll
    for (int i=0;i<2;i++)
      #pragma unroll
      for (int jj=0;jj<2;jj++)
        #pragma unroll
        for (int r=0;r<4;r++) acc[i][jj][r] = 0.f;

    for (int c=0; c<NC; c++){
      const int buf = c & 1;
      // commit prefetched regs to LDS
      #pragma unroll
      for (int q=0;q<4;q++)
        *(uint4*)(&At[buf][(w*32+q*8+sr)*72 + sk*8]) = ra[q];
      if (c < 16)
        *(uint4*)(&Bt[buf][(w*8+sr)*72 + sk*8]) = rb;
      __syncthreads();
      // issue next chunk's global loads (latency overlapped with MFMA below)
      if (c+1 < NC){
        if (c+1 < 16){
          #pragma unroll
          for (int q=0;q<4;q++)
            ra[q] = *(const uint4*)(hsrc + (size_t)(w*32+q*8+sr)*HH + (c+1)*64 + sk*8);
          rb = *(const uint4*)(bw + (size_t)(w*HH + jbase + sr)*HH + (c+1)*64 + sk*8);
        } else {  // x_t chunk (encoder only)
          #pragma unroll
          for (int q=0;q<4;q++)
            ra[q] = *(const uint4*)(src16 + (size_t)(w*32+q*8+sr)*(SS*FF) + t*FF + sk*8);
        }
      }
      // compute this chunk: wave tile 32x32 = 2x2 of 16x16, K=64 (2 sub-chunks)
      const ushort* bsrc = (c==16) ? Wt : &Bt[buf][0];
      #pragma unroll
      for (int kc=0; kc<2; kc++){
        const int kg = kc*4 + fq;
        half8 a0 = *(const half8*)(&At[buf][(w*32 +      fr)*72 + kg*8]);
        half8 a1 = *(const half8*)(&At[buf][(w*32 + 16 + fr)*72 + kg*8]);
        half8 b0 = *(const half8*)(&bsrc[(     fr)*72 + kg*8]);
        half8 b1 = *(const half8*)(&bsrc[(16 + fr)*72 + kg*8]);
        acc[0][0] = __builtin_amdgcn_mfma_f32_16x16x32_f16(a0,b0,acc[0][0],0,0,0);
        acc[0][1] = __builtin_amdgcn_mfma_f32_16x16x32_f16(a0,b1,acc[0][1],0,0,0);
        acc[1][0] = __builtin_amdgcn_mfma_f32_16x16x32_f16(a1,b0,acc[1][0],0,0,0);
        acc[1][1] = __builtin_amdgcn_mfma_f32_16x16x32_f16(a1,b1,acc[1][1],0,0,0);
      }
      // single barrier per chunk: next iter writes the other buffer; its previous
      // readers (compute c-1) are already separated by this iter's barrier.
    }
    __syncthreads();   // all MFMA reads done before Ct overwrites At region

    // C/D frags -> Ct[b][col], col = g*8+jl, stride 33 (conflict-free)
    #pragma unroll
    for (int ti=0; ti<2; ti++)
      #pragma unroll
      for (int tj=0; tj<2; tj++)
        #pragma unroll
        for (int r=0; r<4; r++)
          Ct[(w*32 + ti*16 + fq*4 + r)*33 + tj*16 + fr] = acc[ti][tj][r];
    if (!enc && tid < BB) predacc[tid] = 0.f;
    __syncthreads();

    const int td = t - SS;
    float xb[4];
    if (!enc){
      #pragma unroll
      for (int i=0;i<4;i++) xb[i] = pred[(td%3)*BB + bb + i*32];
    }
    #pragma unroll
    for (int i=0;i<4;i++){
      const int b = bb + i*32;
      float g0 = Ct[b*33 + 0*8 + jl];
      float g1 = Ct[b*33 + 1*8 + jl];
      float g2 = Ct[b*33 + 2*8 + jl];
      float g3 = Ct[b*33 + 3*8 + jl];
      if (enc){
        g0 += ebias[0]; g1 += ebias[1]; g2 += ebias[2]; g3 += ebias[3];
      } else {
        g0 += dbias[0] + xb[i]*dwihv[0];
        g1 += dbias[1] + xb[i]*dwihv[1];
        g2 += dbias[2] + xb[i]*dwihv[2];
        g3 += dbias[3] + xb[i]*dwihv[3];
      }
      float si = sigm(g0), sf = sigm(g1), so = sigm(g3);
      float tg = tanhf(g2);
      cc[i] = sf*cc[i] + si*tg;
      float h2 = so*tanhf(cc[i]);
      h16[(size_t)(p^1)*BB*HH + (size_t)b*HH + jg] = __half_as_ushort(__float2half(h2));
      if (!enc) atomicAdd(&predacc[b], h2*fcwv);
    }
    if (!enc){
      __syncthreads();
      if (tid < BB) atomicAdd(&pred[((td+1)%3)*BB + tid], predacc[tid]);
      if (blockIdx.x == 0 && tid < BB){
        pred[((td+2)%3)*BB + tid] = fcbv;              // pre-init step td+1's acc target
        if (td > 0) out[(size_t)tid*TT + td] = pred[(td%3)*BB + tid];
      }
    }
    p ^= 1;
    gridbar(bar, &barno);
  }
  if (blockIdx.x == 0 && tid < BB)
    out[(size_t)tid*TT + (TT-1)] = pred[((TT-1)%3)*BB + tid];
}

extern "C" void kernel_launch(void* const* d_in, const int* in_sizes, int n_in,
                              void* d_out, int out_size, void* d_ws, size_t ws_size,
                              hipStream_t stream){
  (void)in_sizes; (void)n_in; (void)out_size; (void)ws_size;
  const float* src  = (const float*)d_in[0];
  const float* tgt  = (const float*)d_in[1];
  const float* eWih = (const float*)d_in[2];
  const float* eWhh = (const float*)d_in[3];
  const float* ebih = (const float*)d_in[4];
  const float* ebhh = (const float*)d_in[5];
  const float* dWih = (const float*)d_in[6];
  const float* dWhh = (const float*)d_in[7];
  const float* dbih = (const float*)d_in[8];
  const float* dbhh = (const float*)d_in[9];
  const float* fcW  = (const float*)d_in[10];
  const float* fcb  = (const float*)d_in[11];
  float* out = (float*)d_out;

  // ws carve (ushort units)
  ushort* h16    = (ushort*)d_ws;          // 2*B*H            = 262144
  ushort* src16  = h16    + 2*BB*HH;       // B*S*F            = 4194304
  ushort* wih16  = src16  + BB*SS*FF;      // 4H*F             = 262144
  ushort* ewhh16 = wih16  + 4*HH*FF;       // 4H*H             = 4194304
  ushort* dwhh16 = ewhh16 + 4*HH*HH;       // 4H*H             = 4194304
  float*  pred   = (float*)(dwhh16 + 4*HH*HH);  // 3*B floats
  unsigned* bar  = (unsigned*)(pred + 3*BB);

  hipMemsetAsync(bar, 0, sizeof(unsigned), stream);
  cvt_f32_f16<<<4096, NTHR, 0, stream>>>(src,  src16,  BB*SS*FF);
  cvt_f32_f16<<<1024, NTHR, 0, stream>>>(eWih, wih16,  4*HH*FF);
  cvt_f32_f16<<<4096, NTHR, 0, stream>>>(eWhh, ewhh16, 4*HH*HH);
  cvt_f32_f16<<<4096, NTHR, 0, stream>>>(dWhh, dwhh16, 4*HH*HH);
  seq_kernel<<<dim3(NBLK), dim3(NTHR), 0, stream>>>(
      tgt, src16, wih16, ewhh16, dwhh16, ebih, ebhh, dWih, dbih, dbhh,
      fcW, fcb, out, h16, pred, bar);
}

// Round 4
// 10918.511 us; speedup vs baseline: 4.4140x; 2.0195x over previous
//
#include <hip/hip_runtime.h>
#include <hip/hip_fp16.h>
#include <math.h>

#define BB 128
#define SS 512
#define TT 128
#define FF 64
#define HH 1024

#define NB 4      // batch groups, M=32 each (independent barrier domains)
#define NJ 64     // j-blocks, N=64 each (16 j x 4 gates)
#define NBLK 256
#define NTHR 256  // 4 waves: wn = n-half, wk = k-half
#define PD 8      // a-frag rolling prefetch depth

typedef _Float16 half8 __attribute__((ext_vector_type(8)));
typedef float    f32x16 __attribute__((ext_vector_type(16)));

__device__ __forceinline__ float sigm(float x){ return 1.f/(1.f+expf(-x)); }

// ---- barrier split into arrive / wait (per b-group, 64 blocks) ----
__device__ __forceinline__ void bar_arrive(unsigned* barp, unsigned* barno){
  __syncthreads();                         // drain all threads' stores (vmcnt)
  ++(*barno);
  if (threadIdx.x == 0){ __threadfence(); atomicAdd(barp, 1u); }
}
__device__ __forceinline__ void bar_wait(unsigned* barp, unsigned barno){
  if (threadIdx.x == 0){
    unsigned tgtv = barno * 64u;
    while (__hip_atomic_load(barp, __ATOMIC_RELAXED, __HIP_MEMORY_SCOPE_AGENT) < tgtv)
      __builtin_amdgcn_s_sleep(1);
    __threadfence();
  }
  __syncthreads();
}

// ---- pre-kernels: fp32 -> fp16 ----
__global__ __launch_bounds__(256) void cvt_plain(const float* __restrict__ s,
                                                 ushort* __restrict__ d, int n){
  for (int i = blockIdx.x*256 + threadIdx.x; i < n; i += gridDim.x*256)
    d[i] = __half_as_ushort(__float2half(s[i]));
}
// src [b][s][f] fp32 -> src16T [s][f>>3][b][f&7] fp16 (octet-major for A-frags)
__global__ __launch_bounds__(256) void cvt_src(const float* __restrict__ s,
                                               ushort* __restrict__ d){
  for (int i = blockIdx.x*256 + threadIdx.x; i < BB*SS*FF; i += gridDim.x*256){
    int f = i & 63, st = (i >> 6) & 511, b = i >> 15;
    d[(((size_t)st*8 + (f>>3))*128 + b)*8 + (f&7)] = __half_as_ushort(__float2half(s[i]));
  }
}

// ---- persistent fused seq2seq: B-in-registers, no LDS/syncthreads in K-loop ----
__global__ __launch_bounds__(NTHR, 1) void seq_kernel(
  const float*  __restrict__ tgt,
  const _Float16* __restrict__ src16T,  // [512][8][128][8]
  const _Float16* __restrict__ wih16,   // [4H][64]
  const _Float16* __restrict__ ewhh16,  // [4H][1024]
  const _Float16* __restrict__ dwhh16,  // [4H][1024]
  const float* __restrict__ ebih, const float* __restrict__ ebhh,
  const float* __restrict__ dWih,
  const float* __restrict__ dbih, const float* __restrict__ dbhh,
  const float* __restrict__ fcW, const float* __restrict__ fcb,
  float* __restrict__ out, ushort* h16u, float* predpart, unsigned* bar)
{
  __shared__ float Ct[32*130];     // C staging + k-half reduce + gate transpose
  __shared__ float xacc[2][32];    // decoder x broadcast (parity)
  __shared__ float predsum[32];    // per-block fc partial

  const int tid = threadIdx.x;
  const int wv  = tid >> 6, l = tid & 63;
  const int wn  = wv & 1,  wk = wv >> 1;   // n-half, k-half
  const int nl  = l & 31,  ko = l >> 5;    // lane row, k-octet
  const int btile = blockIdx.x >> 6;       // 0..3
  const int jblk  = blockIdx.x & 63;       // 0..63
  const int m = tid & 31, q = tid >> 5;    // epilogue cell ownership: (m, j=q*2,q*2+1)
  unsigned* barp = bar + btile*16;         // 64B-spaced counters
  unsigned barno = 0;

  const _Float16* h16 = (const _Float16*)h16u;

  // ---- B fragments to registers (once; reloaded at decoder switch) ----
  const int gg0 = (wn*32 + nl) >> 4;
  const int jj0 = (wn*32 + nl) & 15;
  const size_t grow = (size_t)(gg0*HH + jblk*16 + jj0);
  half8 Bh[32];
  #pragma unroll
  for (int s = 0; s < 32; s++)
    Bh[s] = *(const half8*)(ewhh16 + grow*HH + wk*512 + s*16 + ko*8);
  half8 Bx[2];
  #pragma unroll
  for (int s = 0; s < 2; s++)
    Bx[s] = *(const half8*)(wih16 + grow*FF + wk*32 + s*16 + ko*8);

  // ---- per-thread epilogue constants ----
  float ebv[8], wxv[8], fcwv[2];
  #pragma unroll
  for (int g = 0; g < 4; g++)
    #pragma unroll
    for (int u = 0; u < 2; u++){
      int jg = jblk*16 + q*2 + u;
      ebv[g*2+u] = ebih[g*HH + jg] + ebhh[g*HH + jg];
      wxv[g*2+u] = 0.f;
    }
  fcwv[0] = fcwv[1] = 0.f;
  const float fcb0v = fcb[0];

  if (jblk == 0 && tid < 32) out[(size_t)(btile*32 + tid)*TT] = 0.f;  // col 0
  bar_arrive(barp, &barno);   // barrier #0 (uniform counting; h(0) never read)

  float cc0 = 0.f, cc1 = 0.f;   // cell state in registers for all 639 steps
  int p = 0;

  for (int t = 0; t < SS + TT - 1; t++){      // 0..638
    const bool enc = (t < SS);
    f32x16 acc;
    #pragma unroll
    for (int r = 0; r < 16; r++) acc[r] = 0.f;

    if (t == SS){   // decoder switch: swap weights/biases in-register
      #pragma unroll
      for (int s = 0; s < 32; s++)
        Bh[s] = *(const half8*)(dwhh16 + grow*HH + wk*512 + s*16 + ko*8);
      #pragma unroll
      for (int g = 0; g < 4; g++)
        #pragma unroll
        for (int u = 0; u < 2; u++){
          int jg = jblk*16 + q*2 + u;
          ebv[g*2+u] = dbih[g*HH + jg] + dbhh[g*HH + jg];
          wxv[g*2+u] = dWih[g*HH + jg];
        }
      fcwv[0] = fcW[jblk*16 + q*2];
      fcwv[1] = fcW[jblk*16 + q*2 + 1];
    }

    // encoder x-part: loads + MFMA before the barrier wait (src is step-independent)
    if (enc){
      const _Float16* sb = src16T + (((size_t)t*8 + wk*4 + ko)*128 + btile*32 + nl)*8;
      half8 xa0 = *(const half8*)(sb);
      half8 xa1 = *(const half8*)(sb + 2048);
      acc = __builtin_amdgcn_mfma_f32_32x32x16_f16(xa0, Bx[0], acc, 0,0,0);
      acc = __builtin_amdgcn_mfma_f32_32x32x16_f16(xa1, Bx[1], acc, 0,0,0);
    }

    bar_wait(barp, barno);    // h(t) and predpart(t-1) now visible

    float xr = 0.f;
    if (!enc){
      if (t == SS) xr = tgt[(size_t)(btile*32 + m)*TT];   // x0 = target[:,0,0]
      else {
        const float* pp = predpart + ((size_t)((t+1)&1)*NB + btile)*(NJ*32);
        float v = 0.f;
        #pragma unroll
        for (int s = 0; s < 8; s++) v += pp[(q*8 + s)*32 + m];
        atomicAdd(&xacc[t&1][m], v);
        __syncthreads();
        xr = xacc[t&1][m] + fcb0v;
        if (jblk == 0 && tid < 32)
          out[(size_t)(btile*32 + tid)*TT + (t - SS)] = xacc[t&1][tid] + fcb0v;
      }
    }

    // ---- h K-loop: pure global->reg->MFMA, rolling prefetch, no LDS/syncs ----
    if (t > 0){
      const _Float16* hb = h16 + (size_t)p*131072
                         + (((size_t)(wk*64 + ko)*128) + btile*32 + nl)*8;
      half8 pf[PD];
      #pragma unroll
      for (int i = 0; i < PD; i++) pf[i] = *(const half8*)(hb + (size_t)i*2048);
      #pragma unroll
      for (int s = 0; s < 32; s++){
        half8 a = pf[s % PD];
        if (s + PD < 32) pf[s % PD] = *(const half8*)(hb + (size_t)(s + PD)*2048);
        acc = __builtin_amdgcn_mfma_f32_32x32x16_f16(a, Bh[s], acc, 0,0,0);
      }
    }

    // ---- epilogue: k-half reduce + gate transpose through LDS ----
    if (tid < 32) predsum[tid] = 0.f;
    if (tid >= 32 && tid < 64) xacc[(t+1)&1][tid-32] = 0.f;
    #pragma unroll
    for (int r = 0; r < 16; r++){
      int mr = (r & 3) + 8*(r >> 2) + 4*ko;            // C/D row (m74/m101 layout)
      Ct[mr*130 + (wn*32 + nl)*2 + wk] = acc[r];
    }
    __syncthreads();

    float gv[4][2];
    #pragma unroll
    for (int g = 0; g < 4; g++)
      #pragma unroll
      for (int u = 0; u < 2; u++){
        const float* cp = &Ct[m*130 + (g*16 + q*2 + u)*2];
        float s2 = cp[0] + cp[1] + ebv[g*2+u];
        if (!enc) s2 += xr * wxv[g*2+u];
        gv[g][u] = s2;
      }
    float h2v[2];
    #pragma unroll
    for (int u = 0; u < 2; u++){
      float si = sigm(gv[0][u]), sf = sigm(gv[1][u]), so = sigm(gv[3][u]);
      float tg = tanhf(gv[2][u]);
      float c = u ? cc1 : cc0;
      c = sf*c + si*tg;
      if (u) cc1 = c; else cc0 = c;
      h2v[u] = so * tanhf(c);
    }
    {  // h(t+1) store: packed dword into octet-major layout
      int o   = jblk*2 + (q >> 2);
      int off = (q & 3)*2;
      uint hv = (uint)__half_as_ushort(__float2half(h2v[0]))
              | ((uint)__half_as_ushort(__float2half(h2v[1])) << 16);
      *(uint*)(h16u + ((size_t)(p^1)*131072) + ((size_t)o*128 + btile*32 + m)*8 + off) = hv;
    }
    if (!enc){
      atomicAdd(&predsum[m], h2v[0]*fcwv[0] + h2v[1]*fcwv[1]);
      __syncthreads();
      if (tid < 32)
        predpart[((size_t)(t&1)*NB + btile)*(NJ*32) + (size_t)jblk*32 + tid] = predsum[tid];
    }
    p ^= 1;
    bar_arrive(barp, &barno);
  }

  // ---- final column 127 = fc(h(127)) ----
  if (jblk == 0){
    bar_wait(barp, barno);
    const float* pp = predpart + ((size_t)0*NB + btile)*(NJ*32);  // parity of t=638
    float v = 0.f;
    #pragma unroll
    for (int s = 0; s < 8; s++) v += pp[(q*8 + s)*32 + m];
    atomicAdd(&xacc[1][m], v);          // parity 639&1, zeroed at t=638
    __syncthreads();
    if (tid < 32)
      out[(size_t)(btile*32 + tid)*TT + (TT-1)] = xacc[1][tid] + fcb0v;
  }
}

extern "C" void kernel_launch(void* const* d_in, const int* in_sizes, int n_in,
                              void* d_out, int out_size, void* d_ws, size_t ws_size,
                              hipStream_t stream){
  (void)in_sizes; (void)n_in; (void)out_size; (void)ws_size;
  const float* src  = (const float*)d_in[0];
  const float* tgt  = (const float*)d_in[1];
  const float* eWih = (const float*)d_in[2];
  const float* eWhh = (const float*)d_in[3];
  const float* ebih = (const float*)d_in[4];
  const float* ebhh = (const float*)d_in[5];
  const float* dWih = (const float*)d_in[6];
  const float* dWhh = (const float*)d_in[7];
  const float* dbih = (const float*)d_in[8];
  const float* dbhh = (const float*)d_in[9];
  const float* fcW  = (const float*)d_in[10];
  const float* fcb  = (const float*)d_in[11];
  float* out = (float*)d_out;

  // ws carve (ushort units)
  ushort* h16    = (ushort*)d_ws;          // 2*128*128*8      = 262144
  ushort* src16T = h16    + 262144;        // 512*8*128*8      = 4194304
  ushort* wih16  = src16T + 4194304;       // 4096*64          = 262144
  ushort* ewhh16 = wih16  + 262144;        // 4096*1024        = 4194304
  ushort* dwhh16 = ewhh16 + 4194304;       // 4096*1024        = 4194304
  float*  predpart = (float*)(dwhh16 + 4194304);   // 2*4*64*32 = 16384 floats
  unsigned* bar  = (unsigned*)(predpart + 16384);  // 4 x 64B

  hipMemsetAsync(bar, 0, 256, stream);
  cvt_src  <<<4096, 256, 0, stream>>>(src, src16T);
  cvt_plain<<<1024, 256, 0, stream>>>(eWih, wih16,  4*HH*FF);
  cvt_plain<<<4096, 256, 0, stream>>>(eWhh, ewhh16, 4*HH*HH);
  cvt_plain<<<4096, 256, 0, stream>>>(dWhh, dwhh16, 4*HH*HH);
  seq_kernel<<<dim3(NBLK), dim3(NTHR), 0, stream>>>(
      tgt, (const _Float16*)src16T, (const _Float16*)wih16,
      (const _Float16*)ewhh16, (const _Float16*)dwhh16,
      ebih, ebhh, dWih, dbih, dbhh, fcW, fcb, out, h16, predpart, bar);
}

// Round 5
// 3843.970 us; speedup vs baseline: 12.5375x; 2.8404x over previous
//
#include <hip/hip_runtime.h>
#include <hip/hip_fp16.h>
#include <math.h>

#define BB 128
#define SS 512
#define TT 128
#define FF 64
#define HH 1024

#define NBLK 256   // 4 b-groups x 64 j-blocks
#define NTHR 256   // 4 waves, wave = k-quarter (K=256 each), full N=64

typedef _Float16 half8 __attribute__((ext_vector_type(8)));
typedef float    f32x16 __attribute__((ext_vector_type(16)));
typedef unsigned long long u64;

__device__ __forceinline__ float sigm(float x){ return 1.f/(1.f+expf(-x)); }

// ---- IF$-coherent accessors (sc1: bypass per-XCD L2; no fences needed) ----
__device__ __forceinline__ u64 aload64(const void* p){
  return __hip_atomic_load((const u64*)p, __ATOMIC_RELAXED, __HIP_MEMORY_SCOPE_AGENT);
}
__device__ __forceinline__ float aloadf(const float* p){
  return __hip_atomic_load(p, __ATOMIC_RELAXED, __HIP_MEMORY_SCOPE_AGENT);
}
__device__ __forceinline__ void astoref(float* p, float v){
  __hip_atomic_store(p, v, __ATOMIC_RELAXED, __HIP_MEMORY_SCOPE_AGENT);
}
__device__ __forceinline__ void astoreu(unsigned* p, unsigned v){
  __hip_atomic_store(p, v, __ATOMIC_RELAXED, __HIP_MEMORY_SCOPE_AGENT);
}

// ---- fence-free barrier: vmcnt drain + s_barrier IS the release; readers use sc1 ----
__device__ __forceinline__ void bar_arrive(unsigned* barp, unsigned* barno){
  asm volatile("s_waitcnt vmcnt(0)" ::: "memory");  // per-wave: all sc1 stores visible at IF$
  __syncthreads();
  ++(*barno);
  if (threadIdx.x == 0) atomicAdd(barp, 1u);        // agent-scope (m20)
}
__device__ __forceinline__ void bar_wait(unsigned* barp, unsigned barno){
  if (threadIdx.x == 0){
    unsigned tgt = barno * 64u;
    while (__hip_atomic_load(barp, __ATOMIC_RELAXED, __HIP_MEMORY_SCOPE_AGENT) < tgt)
      __builtin_amdgcn_s_sleep(1);
  }
  __syncthreads();   // compiler+HW barrier; subsequent sc1 loads can't hoist above
}

// ---- pre-kernels: fp32 -> fp16 ----
__global__ __launch_bounds__(256) void cvt_plain(const float* __restrict__ s,
                                                 ushort* __restrict__ d, int n){
  for (int i = blockIdx.x*256 + threadIdx.x; i < n; i += gridDim.x*256)
    d[i] = __half_as_ushort(__float2half(s[i]));
}
// src [b][s][f] -> src16T [s][f>>3][b][f&7]
__global__ __launch_bounds__(256) void cvt_src(const float* __restrict__ s,
                                               ushort* __restrict__ d){
  for (int i = blockIdx.x*256 + threadIdx.x; i < BB*SS*FF; i += gridDim.x*256){
    int f = i & 63, st = (i >> 6) & 511, b = i >> 15;
    d[(((size_t)st*8 + (f>>3))*128 + b)*8 + (f&7)] = __half_as_ushort(__float2half(s[i]));
  }
}

__global__ __launch_bounds__(NTHR, 1) void seq_kernel(
  const float*  __restrict__ tgt,
  const _Float16* __restrict__ src16T,  // [512][8][128][8]
  const _Float16* __restrict__ wih16,   // [4H][64]
  const _Float16* __restrict__ ewhh16,  // [4H][1024]
  const _Float16* __restrict__ dwhh16,  // [4H][1024]
  const float* __restrict__ ebih, const float* __restrict__ ebhh,
  const float* __restrict__ dWih,
  const float* __restrict__ dbih, const float* __restrict__ dbhh,
  const float* __restrict__ fcW, const float* __restrict__ fcb,
  float* __restrict__ out, ushort* h16u, float* predpart, unsigned* bar)
{
  __shared__ float Ct4[4][32][68];   // [wk][m][n], 68-pad: conflict-free dword writes
  __shared__ float xacc[2][32];
  __shared__ float predsum[32];

  const int tid = threadIdx.x;
  const int wk  = tid >> 6;              // k-quarter
  const int l   = tid & 63;
  const int nl  = l & 31, ko = l >> 5;   // lane row / k-octet
  const int btile = blockIdx.x >> 6;
  const int jblk  = blockIdx.x & 63;
  const int m = tid & 31, q = tid >> 5;  // epilogue: (b=m, jj=2q,2q+1)
  unsigned* barp = bar + btile*16;
  unsigned barno = 0;

  const _Float16* h16 = (const _Float16*)h16u;

  // ---- B fragments to registers: [s][n-half], K-quarter wk ----
  half8 Bh[32];
  #pragma unroll
  for (int s = 0; s < 16; s++)
    #pragma unroll
    for (int h = 0; h < 2; h++){
      int nn = h*32 + nl;
      size_t grow = (size_t)((nn>>4)*HH + jblk*16 + (nn&15));
      Bh[s*2+h] = *(const half8*)(ewhh16 + grow*HH + wk*256 + s*16 + ko*8);
    }
  half8 Bx[2];
  #pragma unroll
  for (int h = 0; h < 2; h++){
    int nn = h*32 + nl;
    size_t grow = (size_t)((nn>>4)*HH + jblk*16 + (nn&15));
    Bx[h] = *(const half8*)(wih16 + grow*FF + wk*16 + ko*8);
  }

  // ---- per-thread epilogue constants ----
  float ebv[8], wxv[8], fcwv[2];
  #pragma unroll
  for (int g = 0; g < 4; g++)
    #pragma unroll
    for (int u = 0; u < 2; u++){
      int jg = jblk*16 + 2*q + u;
      ebv[g*2+u] = ebih[g*HH + jg] + ebhh[g*HH + jg];
      wxv[g*2+u] = 0.f;
    }
  fcwv[0] = fcwv[1] = 0.f;
  const float fcb0v = fcb[0];

  if (jblk == 0 && tid < 32) out[(size_t)(btile*32 + tid)*TT] = 0.f;
  bar_arrive(barp, &barno);

  float cc0 = 0.f, cc1 = 0.f;
  int p = 0;

  for (int t = 0; t < SS + TT - 1; t++){
    const bool enc = (t < SS);
    f32x16 acc0, acc1;
    #pragma unroll
    for (int r = 0; r < 16; r++){ acc0[r] = 0.f; acc1[r] = 0.f; }

    if (t == SS){
      #pragma unroll
      for (int s = 0; s < 16; s++)
        #pragma unroll
        for (int h = 0; h < 2; h++){
          int nn = h*32 + nl;
          size_t grow = (size_t)((nn>>4)*HH + jblk*16 + (nn&15));
          Bh[s*2+h] = *(const half8*)(dwhh16 + grow*HH + wk*256 + s*16 + ko*8);
        }
      #pragma unroll
      for (int g = 0; g < 4; g++)
        #pragma unroll
        for (int u = 0; u < 2; u++){
          int jg = jblk*16 + 2*q + u;
          ebv[g*2+u] = dbih[g*HH + jg] + dbhh[g*HH + jg];
          wxv[g*2+u] = dWih[g*HH + jg];
        }
      fcwv[0] = fcW[jblk*16 + 2*q];
      fcwv[1] = fcW[jblk*16 + 2*q + 1];
    }

    // encoder x-part before barrier (step-independent input, normal cached loads)
    if (enc){
      half8 xa = *(const half8*)(src16T + (((size_t)t*8 + wk*2 + ko)*128 + btile*32 + nl)*8);
      acc0 = __builtin_amdgcn_mfma_f32_32x32x16_f16(xa, Bx[0], acc0, 0,0,0);
      acc1 = __builtin_amdgcn_mfma_f32_32x32x16_f16(xa, Bx[1], acc1, 0,0,0);
    }

    bar_wait(barp, barno);   // h(t)/predpart(t-1) visible at IF$

    // decoder: issue pred partial loads now; consume after K-loop (latency hidden)
    float pv[8];
    if (!enc && t > SS){
      const float* pp = predpart + ((size_t)((t+1)&1)*4 + btile)*2048;
      #pragma unroll
      for (int s = 0; s < 8; s++) pv[s] = aloadf(pp + (q*8+s)*32 + m);
    }

    // ---- h K-loop: sc1 loads -> MFMA, no LDS, no syncs ----
    if (t > 0){
      const _Float16* hp = h16 + (size_t)p*131072
                         + (((size_t)(wk*32 + ko)*128) + btile*32 + nl)*8;
      u64 pf[32];
      #pragma unroll
      for (int s = 0; s < 16; s++){
        const u64* ap = (const u64*)(hp + (size_t)s*2048);
        pf[2*s]   = aload64(ap);
        pf[2*s+1] = aload64(ap+1);
      }
      #pragma unroll
      for (int s = 0; s < 16; s++){
        union { u64 qq[2]; half8 v; } ua;
        ua.qq[0] = pf[2*s]; ua.qq[1] = pf[2*s+1];
        acc0 = __builtin_amdgcn_mfma_f32_32x32x16_f16(ua.v, Bh[2*s],   acc0, 0,0,0);
        acc1 = __builtin_amdgcn_mfma_f32_32x32x16_f16(ua.v, Bh[2*s+1], acc1, 0,0,0);
      }
    }

    // ---- epilogue: 4-way k-reduce + gate transpose through LDS ----
    if (tid < 32) predsum[tid] = 0.f;
    if (tid >= 32 && tid < 64) xacc[(t+1)&1][tid-32] = 0.f;
    #pragma unroll
    for (int r = 0; r < 16; r++){
      int mr = (r & 3) + 8*(r >> 2) + 4*ko;     // C/D row map (m74/m101)
      Ct4[wk][mr][nl]      = acc0[r];
      Ct4[wk][mr][32 + nl] = acc1[r];
    }
    float xr = 0.f;
    if (!enc){
      if (t == SS) xr = tgt[(size_t)(btile*32 + m)*TT];
      else {
        float v = ((pv[0]+pv[1])+(pv[2]+pv[3])) + ((pv[4]+pv[5])+(pv[6]+pv[7]));
        atomicAdd(&xacc[t&1][m], v);
      }
    }
    __syncthreads();
    if (!enc && t > SS){
      xr = xacc[t&1][m] + fcb0v;
      if (jblk == 0 && tid < 32)
        out[(size_t)(btile*32 + tid)*TT + (t - SS)] = xacc[t&1][tid] + fcb0v;
    }

    float gv[8];
    #pragma unroll
    for (int g = 0; g < 4; g++)
      #pragma unroll
      for (int u = 0; u < 2; u++){
        int n = g*16 + 2*q + u;
        float s2 = ((Ct4[0][m][n] + Ct4[1][m][n]) + (Ct4[2][m][n] + Ct4[3][m][n]))
                 + ebv[g*2+u];
        if (!enc) s2 += xr * wxv[g*2+u];
        gv[g*2+u] = s2;
      }
    float h2[2];
    #pragma unroll
    for (int u = 0; u < 2; u++){
      float si = sigm(gv[0+u]), sf = sigm(gv[2+u]), so = sigm(gv[6+u]);
      float tg = tanhf(gv[4+u]);
      float c = u ? cc1 : cc0;
      c = sf*c + si*tg;
      if (u) cc1 = c; else cc0 = c;
      h2[u] = so * tanhf(c);
    }
    {  // h(t+1) store: packed dword, sc1 write-through to IF$
      int o = jblk*2 + (q >> 2), off = (q & 3)*2;
      unsigned hv = (unsigned)__half_as_ushort(__float2half(h2[0]))
                  | ((unsigned)__half_as_ushort(__float2half(h2[1])) << 16);
      astoreu((unsigned*)(h16u + (size_t)(p^1)*131072
                          + ((size_t)o*128 + btile*32 + m)*8 + off), hv);
    }
    if (!enc){
      atomicAdd(&predsum[m], h2[0]*fcwv[0] + h2[1]*fcwv[1]);
      __syncthreads();
      if (tid < 32)
        astoref(predpart + ((size_t)(t&1)*4 + btile)*2048 + (size_t)jblk*32 + tid,
                predsum[tid]);
    }
    p ^= 1;
    bar_arrive(barp, &barno);
  }

  // ---- final column 127 = fc(h(127)) ----
  if (jblk == 0){
    bar_wait(barp, barno);
    const float* pp = predpart + (size_t)btile*2048;   // parity of t=638 is 0
    float v = 0.f;
    #pragma unroll
    for (int s = 0; s < 8; s++) v += aloadf(pp + (q*8+s)*32 + m);
    atomicAdd(&xacc[1][m], v);                         // zeroed at t=638
    __syncthreads();
    if (tid < 32)
      out[(size_t)(btile*32 + tid)*TT + (TT-1)] = xacc[1][tid] + fcb0v;
  }
}

extern "C" void kernel_launch(void* const* d_in, const int* in_sizes, int n_in,
                              void* d_out, int out_size, void* d_ws, size_t ws_size,
                              hipStream_t stream){
  (void)in_sizes; (void)n_in; (void)out_size; (void)ws_size;
  const float* src  = (const float*)d_in[0];
  const float* tgt  = (const float*)d_in[1];
  const float* eWih = (const float*)d_in[2];
  const float* eWhh = (const float*)d_in[3];
  const float* ebih = (const float*)d_in[4];
  const float* ebhh = (const float*)d_in[5];
  const float* dWih = (const float*)d_in[6];
  const float* dWhh = (const float*)d_in[7];
  const float* dbih = (const float*)d_in[8];
  const float* dbhh = (const float*)d_in[9];
  const float* fcW  = (const float*)d_in[10];
  const float* fcb  = (const float*)d_in[11];
  float* out = (float*)d_out;

  ushort* h16    = (ushort*)d_ws;          // 2*128*128*8      = 262144
  ushort* src16T = h16    + 262144;        // 512*8*128*8      = 4194304
  ushort* wih16  = src16T + 4194304;       // 4096*64          = 262144
  ushort* ewhh16 = wih16  + 262144;        // 4096*1024        = 4194304
  ushort* dwhh16 = ewhh16 + 4194304;       // 4096*1024        = 4194304
  float*  predpart = (float*)(dwhh16 + 4194304);   // 2*4*64*32 floats
  unsigned* bar  = (unsigned*)(predpart + 16384);  // 4 x 64B

  hipMemsetAsync(bar, 0, 256, stream);
  cvt_src  <<<4096, 256, 0, stream>>>(src, src16T);
  cvt_plain<<<1024, 256, 0, stream>>>(eWih, wih16,  4*HH*FF);
  cvt_plain<<<4096, 256, 0, stream>>>(eWhh, ewhh16, 4*HH*HH);
  cvt_plain<<<4096, 256, 0, stream>>>(dWhh, dwhh16, 4*HH*HH);
  seq_kernel<<<dim3(NBLK), dim3(NTHR), 0, stream>>>(
      tgt, (const _Float16*)src16T, (const _Float16*)wih16,
      (const _Float16*)ewhh16, (const _Float16*)dwhh16,
      ebih, ebhh, dWih, dbih, dbhh, fcW, fcb, out, h16, predpart, bar);
}

// Round 6
// 3411.111 us; speedup vs baseline: 14.1285x; 1.1269x over previous
//
#include <hip/hip_runtime.h>
#include <hip/hip_fp16.h>
#include <math.h>

#define BB 128
#define SS 512
#define TT 128
#define FF 64
#define HH 1024

#define NBLK 256   // 4 b-groups x 64 j-blocks
#define NTHR 256   // 4 waves, wave = k-quarter (K=256 each), full N=64

typedef _Float16 half8 __attribute__((ext_vector_type(8)));
typedef float    f32x16 __attribute__((ext_vector_type(16)));
typedef unsigned long long u64;

// ---- fast transcendentals: v_exp_f32 + v_rcp_f32 (rel err ~1e-6 << fp16 noise) ----
__device__ __forceinline__ float rcpf(float x){ return __builtin_amdgcn_rcpf(x); }
__device__ __forceinline__ float sigm(float x){ return rcpf(1.f + __expf(-x)); }
__device__ __forceinline__ float tfast(float x){
  float a = fabsf(x);
  float e = __expf(-2.f*a);
  float t = (1.f - e) * rcpf(1.f + e);
  return copysignf(t, x);
}

// ---- IF$-coherent accessors (sc1: bypass per-XCD L2; no fences needed) ----
__device__ __forceinline__ u64 aload64(const void* p){
  return __hip_atomic_load((const u64*)p, __ATOMIC_RELAXED, __HIP_MEMORY_SCOPE_AGENT);
}
__device__ __forceinline__ float aloadf(const float* p){
  return __hip_atomic_load(p, __ATOMIC_RELAXED, __HIP_MEMORY_SCOPE_AGENT);
}
__device__ __forceinline__ void astoref(float* p, float v){
  __hip_atomic_store(p, v, __ATOMIC_RELAXED, __HIP_MEMORY_SCOPE_AGENT);
}
__device__ __forceinline__ void astoreu(unsigned* p, unsigned v){
  __hip_atomic_store(p, v, __ATOMIC_RELAXED, __HIP_MEMORY_SCOPE_AGENT);
}

// ---- contention-free flag barrier ----
// arrive: vmcnt drain (h stores ack'd at IF$) + s_barrier, then ONE plain sc1
// store to this block's own flag — no RMW, no same-address serialization.
__device__ __forceinline__ void bar_arrive(unsigned* flags, int jblk, unsigned* barno){
  asm volatile("s_waitcnt vmcnt(0)" ::: "memory");
  __syncthreads();                    // all 4 waves' sc1 stores drained
  ++(*barno);
  if (threadIdx.x == 0) astoreu(&flags[jblk], *barno);
}
// wait: wave 0's 64 lanes each poll one flag (one coalesced 256B sc1 load/iter);
// exec-mask divergence gives __all semantics for free.
__device__ __forceinline__ void bar_wait(const unsigned* flags, unsigned barno){
  if (threadIdx.x < 64){
    while (__hip_atomic_load(&flags[threadIdx.x], __ATOMIC_RELAXED,
                             __HIP_MEMORY_SCOPE_AGENT) < barno) {}
  }
  __syncthreads();
}

// ---- pre-kernels: fp32 -> fp16 ----
__global__ __launch_bounds__(256) void cvt_plain(const float* __restrict__ s,
                                                 ushort* __restrict__ d, int n){
  for (int i = blockIdx.x*256 + threadIdx.x; i < n; i += gridDim.x*256)
    d[i] = __half_as_ushort(__float2half(s[i]));
}
// src [b][s][f] -> src16T [s][f>>3][b][f&7]
__global__ __launch_bounds__(256) void cvt_src(const float* __restrict__ s,
                                               ushort* __restrict__ d){
  for (int i = blockIdx.x*256 + threadIdx.x; i < BB*SS*FF; i += gridDim.x*256){
    int f = i & 63, st = (i >> 6) & 511, b = i >> 15;
    d[(((size_t)st*8 + (f>>3))*128 + b)*8 + (f&7)] = __half_as_ushort(__float2half(s[i]));
  }
}

__global__ __launch_bounds__(NTHR, 1) void seq_kernel(
  const float*  __restrict__ tgt,
  const _Float16* __restrict__ src16T,  // [512][8][128][8]
  const _Float16* __restrict__ wih16,   // [4H][64]
  const _Float16* __restrict__ ewhh16,  // [4H][1024]
  const _Float16* __restrict__ dwhh16,  // [4H][1024]
  const float* __restrict__ ebih, const float* __restrict__ ebhh,
  const float* __restrict__ dWih,
  const float* __restrict__ dbih, const float* __restrict__ dbhh,
  const float* __restrict__ fcW, const float* __restrict__ fcb,
  float* __restrict__ out, ushort* h16u, float* predpart, unsigned* barflags)
{
  __shared__ float Ct4[4][32][68];   // [wk][m][n], 68-pad: conflict-free dword writes
  __shared__ float xacc[2][32];
  __shared__ float predsum[32];

  const int tid = threadIdx.x;
  const int wk  = tid >> 6;              // k-quarter
  const int l   = tid & 63;
  const int nl  = l & 31, ko = l >> 5;   // lane row / k-octet
  const int btile = blockIdx.x >> 6;
  const int jblk  = blockIdx.x & 63;
  const int m = tid & 31, q = tid >> 5;  // epilogue: (b=m, jj=2q,2q+1)
  unsigned* flags = barflags + btile*64; // 256B per btile, line-exclusive
  unsigned barno = 0;

  const _Float16* h16 = (const _Float16*)h16u;

  // ---- B fragments to registers: [s][n-half], K-quarter wk ----
  half8 Bh[32];
  #pragma unroll
  for (int s = 0; s < 16; s++)
    #pragma unroll
    for (int h = 0; h < 2; h++){
      int nn = h*32 + nl;
      size_t grow = (size_t)((nn>>4)*HH + jblk*16 + (nn&15));
      Bh[s*2+h] = *(const half8*)(ewhh16 + grow*HH + wk*256 + s*16 + ko*8);
    }
  half8 Bx[2];
  #pragma unroll
  for (int h = 0; h < 2; h++){
    int nn = h*32 + nl;
    size_t grow = (size_t)((nn>>4)*HH + jblk*16 + (nn&15));
    Bx[h] = *(const half8*)(wih16 + grow*FF + wk*16 + ko*8);
  }

  // ---- per-thread epilogue constants ----
  float ebv[8], wxv[8], fcwv[2];
  #pragma unroll
  for (int g = 0; g < 4; g++)
    #pragma unroll
    for (int u = 0; u < 2; u++){
      int jg = jblk*16 + 2*q + u;
      ebv[g*2+u] = ebih[g*HH + jg] + ebhh[g*HH + jg];
      wxv[g*2+u] = 0.f;
    }
  fcwv[0] = fcwv[1] = 0.f;
  const float fcb0v = fcb[0];

  if (jblk == 0 && tid < 32) out[(size_t)(btile*32 + tid)*TT] = 0.f;
  bar_arrive(flags, jblk, &barno);

  float cc0 = 0.f, cc1 = 0.f;
  int p = 0;

  for (int t = 0; t < SS + TT - 1; t++){
    const bool enc = (t < SS);
    f32x16 acc0, acc1;
    #pragma unroll
    for (int r = 0; r < 16; r++){ acc0[r] = 0.f; acc1[r] = 0.f; }

    if (t == SS){
      #pragma unroll
      for (int s = 0; s < 16; s++)
        #pragma unroll
        for (int h = 0; h < 2; h++){
          int nn = h*32 + nl;
          size_t grow = (size_t)((nn>>4)*HH + jblk*16 + (nn&15));
          Bh[s*2+h] = *(const half8*)(dwhh16 + grow*HH + wk*256 + s*16 + ko*8);
        }
      #pragma unroll
      for (int g = 0; g < 4; g++)
        #pragma unroll
        for (int u = 0; u < 2; u++){
          int jg = jblk*16 + 2*q + u;
          ebv[g*2+u] = dbih[g*HH + jg] + dbhh[g*HH + jg];
          wxv[g*2+u] = dWih[g*HH + jg];
        }
      fcwv[0] = fcW[jblk*16 + 2*q];
      fcwv[1] = fcW[jblk*16 + 2*q + 1];
    }

    // encoder x-part before barrier (step-independent input, normal cached loads)
    if (enc){
      half8 xa = *(const half8*)(src16T + (((size_t)t*8 + wk*2 + ko)*128 + btile*32 + nl)*8);
      acc0 = __builtin_amdgcn_mfma_f32_32x32x16_f16(xa, Bx[0], acc0, 0,0,0);
      acc1 = __builtin_amdgcn_mfma_f32_32x32x16_f16(xa, Bx[1], acc1, 0,0,0);
    }

    bar_wait(flags, barno);   // h(t)/predpart(t-1) visible at IF$

    // decoder: issue pred partial loads now; consume after K-loop (latency hidden)
    float pv[8];
    if (!enc && t > SS){
      const float* pp = predpart + ((size_t)((t+1)&1)*4 + btile)*2048;
      #pragma unroll
      for (int s = 0; s < 8; s++) pv[s] = aloadf(pp + (q*8+s)*32 + m);
    }

    // ---- h K-loop: sc1 loads -> MFMA, no LDS, no syncs ----
    if (t > 0){
      const _Float16* hp = h16 + (size_t)p*131072
                         + (((size_t)(wk*32 + ko)*128) + btile*32 + nl)*8;
      u64 pf[32];
      #pragma unroll
      for (int s = 0; s < 16; s++){
        const u64* ap = (const u64*)(hp + (size_t)s*2048);
        pf[2*s]   = aload64(ap);
        pf[2*s+1] = aload64(ap+1);
      }
      #pragma unroll
      for (int s = 0; s < 16; s++){
        union { u64 qq[2]; half8 v; } ua;
        ua.qq[0] = pf[2*s]; ua.qq[1] = pf[2*s+1];
        acc0 = __builtin_amdgcn_mfma_f32_32x32x16_f16(ua.v, Bh[2*s],   acc0, 0,0,0);
        acc1 = __builtin_amdgcn_mfma_f32_32x32x16_f16(ua.v, Bh[2*s+1], acc1, 0,0,0);
      }
    }

    // ---- epilogue: 4-way k-reduce + gate transpose through LDS ----
    if (tid < 32) predsum[tid] = 0.f;
    if (tid >= 32 && tid < 64) xacc[(t+1)&1][tid-32] = 0.f;
    #pragma unroll
    for (int r = 0; r < 16; r++){
      int mr = (r & 3) + 8*(r >> 2) + 4*ko;     // C/D row map (m74/m101)
      Ct4[wk][mr][nl]      = acc0[r];
      Ct4[wk][mr][32 + nl] = acc1[r];
    }
    float xr = 0.f;
    if (!enc){
      if (t == SS) xr = tgt[(size_t)(btile*32 + m)*TT];
      else {
        float v = ((pv[0]+pv[1])+(pv[2]+pv[3])) + ((pv[4]+pv[5])+(pv[6]+pv[7]));
        atomicAdd(&xacc[t&1][m], v);
      }
    }
    __syncthreads();
    if (!enc && t > SS){
      xr = xacc[t&1][m] + fcb0v;
      if (jblk == 0 && tid < 32)
        out[(size_t)(btile*32 + tid)*TT + (t - SS)] = xacc[t&1][tid] + fcb0v;
    }

    float gv[8];
    #pragma unroll
    for (int g = 0; g < 4; g++)
      #pragma unroll
      for (int u = 0; u < 2; u++){
        int n = g*16 + 2*q + u;
        float s2 = ((Ct4[0][m][n] + Ct4[1][m][n]) + (Ct4[2][m][n] + Ct4[3][m][n]))
                 + ebv[g*2+u];
        if (!enc) s2 += xr * wxv[g*2+u];
        gv[g*2+u] = s2;
      }
    float h2[2];
    #pragma unroll
    for (int u = 0; u < 2; u++){
      float si = sigm(gv[0+u]), sf = sigm(gv[2+u]), so = sigm(gv[6+u]);
      float tg = tfast(gv[4+u]);
      float c = u ? cc1 : cc0;
      c = sf*c + si*tg;
      if (u) cc1 = c; else cc0 = c;
      h2[u] = so * tfast(c);
    }
    {  // h(t+1) store: packed dword, sc1 write-through to IF$
      int o = jblk*2 + (q >> 2), off = (q & 3)*2;
      unsigned hv = (unsigned)__half_as_ushort(__float2half(h2[0]))
                  | ((unsigned)__half_as_ushort(__float2half(h2[1])) << 16);
      astoreu((unsigned*)(h16u + (size_t)(p^1)*131072
                          + ((size_t)o*128 + btile*32 + m)*8 + off), hv);
    }
    if (!enc){
      atomicAdd(&predsum[m], h2[0]*fcwv[0] + h2[1]*fcwv[1]);
      __syncthreads();
      if (tid < 32)
        astoref(predpart + ((size_t)(t&1)*4 + btile)*2048 + (size_t)jblk*32 + tid,
                predsum[tid]);
    }
    p ^= 1;
    bar_arrive(flags, jblk, &barno);
  }

  // ---- final column 127 = fc(h(127)) ----
  if (jblk == 0){
    bar_wait(flags, barno);
    const float* pp = predpart + (size_t)btile*2048;   // parity of t=638 is 0
    float v = 0.f;
    #pragma unroll
    for (int s = 0; s < 8; s++) v += aloadf(pp + (q*8+s)*32 + m);
    atomicAdd(&xacc[1][m], v);                         // zeroed at t=638
    __syncthreads();
    if (tid < 32)
      out[(size_t)(btile*32 + tid)*TT + (TT-1)] = xacc[1][tid] + fcb0v;
  }
}

extern "C" void kernel_launch(void* const* d_in, const int* in_sizes, int n_in,
                              void* d_out, int out_size, void* d_ws, size_t ws_size,
                              hipStream_t stream){
  (void)in_sizes; (void)n_in; (void)out_size; (void)ws_size;
  const float* src  = (const float*)d_in[0];
  const float* tgt  = (const float*)d_in[1];
  const float* eWih = (const float*)d_in[2];
  const float* eWhh = (const float*)d_in[3];
  const float* ebih = (const float*)d_in[4];
  const float* ebhh = (const float*)d_in[5];
  const float* dWih = (const float*)d_in[6];
  const float* dWhh = (const float*)d_in[7];
  const float* dbih = (const float*)d_in[8];
  const float* dbhh = (const float*)d_in[9];
  const float* fcW  = (const float*)d_in[10];
  const float* fcb  = (const float*)d_in[11];
  float* out = (float*)d_out;

  ushort* h16    = (ushort*)d_ws;          // 2*128*128*8      = 262144
  ushort* src16T = h16    + 262144;        // 512*8*128*8      = 4194304
  ushort* wih16  = src16T + 4194304;       // 4096*64          = 262144
  ushort* ewhh16 = wih16  + 262144;        // 4096*1024        = 4194304
  ushort* dwhh16 = ewhh16 + 4194304;       // 4096*1024        = 4194304
  float*  predpart = (float*)(dwhh16 + 4194304);   // 2*4*64*32 floats
  unsigned* barflags = (unsigned*)(predpart + 16384);  // 4 btiles x 64 dwords (256B each)

  hipMemsetAsync(barflags, 0, 4*64*sizeof(unsigned), stream);
  cvt_src  <<<4096, 256, 0, stream>>>(src, src16T);
  cvt_plain<<<1024, 256, 0, stream>>>(eWih, wih16,  4*HH*FF);
  cvt_plain<<<4096, 256, 0, stream>>>(eWhh, ewhh16, 4*HH*HH);
  cvt_plain<<<4096, 256, 0, stream>>>(dWhh, dwhh16, 4*HH*HH);
  seq_kernel<<<dim3(NBLK), dim3(NTHR), 0, stream>>>(
      tgt, (const _Float16*)src16T, (const _Float16*)wih16,
      (const _Float16*)ewhh16, (const _Float16*)dwhh16,
      ebih, ebhh, dWih, dbih, dbhh, fcW, fcb, out, h16, predpart, barflags);
}